// Round 12
// baseline (147.541 us; speedup 1.0000x reference)
//
#include <hip/hip_runtime.h>
#include <hip/hip_bf16.h>

typedef __bf16 bf16;
typedef __bf16 bf16x4 __attribute__((ext_vector_type(4)));
typedef __bf16 bf16x8 __attribute__((ext_vector_type(8)));
typedef float floatx4 __attribute__((ext_vector_type(4)));

#define D_MODEL 512
#define NHEAD 8
#define HD 64
#define NB 2
#define NN 2048
#define BH (NB*NHEAD)
#define LOG2E 1.4426950408889634f

// ---------------- kernel 0: convert x,w fp32 -> bf16; fused coord projection ----------------
__global__ __launch_bounds__(256) void convxw(const float* __restrict__ x,
                                              const float* __restrict__ w,
                                              const float* __restrict__ coords,
                                              const float* __restrict__ rw,
                                              bf16* __restrict__ xb,
                                              bf16* __restrict__ wb,
                                              float* __restrict__ cp) {
    int bid = blockIdx.x;
    if (bid >= 2816) {
        // coordproj tail: 16 blocks, cp pre-scaled by log2(e) for exp2-domain softmax
        int idx = (bid - 2816) * 256 + threadIdx.x;
        int b = idx >> 11, n = idx & 2047;
        float c0 = coords[idx*3 + 0];
        float c1 = coords[idx*3 + 1];
        float c2 = coords[idx*3 + 2];
        for (int h = 0; h < NHEAD; h++) {
            float v = c0*rw[h*3+0] + c1*rw[h*3+1] + c2*rw[h*3+2];
            cp[(size_t)(b*NHEAD + h)*NN + n] = v * LOG2E;
        }
        return;
    }
    int idx = bid * 256 + threadIdx.x;
    const float* src; bf16* dst; int i4;
    if (idx < 524288) { src = x; dst = xb; i4 = idx; }
    else              { src = w; dst = wb; i4 = idx - 524288; }
    float4 v = *(const float4*)(src + (size_t)i4*4);
    bf16x4 o; o[0] = (bf16)v.x; o[1] = (bf16)v.y; o[2] = (bf16)v.z; o[3] = (bf16)v.w;
    *(bf16x4*)(dst + (size_t)i4*4) = o;
}

// ---------------- kernel 2: QKV GEMM, C^T = W * X^T (bf16 inputs) ----------------
// Tile: 64 features x 128 rows, K=512. 768 blocks, 256 thr / 4 waves.
// Register prefetch of k-tile k+1 issued after the staging barrier (attn's
// proven pattern): the 6x16B loads get a full MFMA phase of latency hiding
// instead of serially stalling at the top of each iteration.
// Q is pre-scaled by 0.125*log2(e) so attention works in exp2 domain.
__global__ __launch_bounds__(256, 4) void qkv_gemm(const bf16* __restrict__ xb,
                                                   const bf16* __restrict__ wb,
                                                   const float* __restrict__ bias,
                                                   bf16* __restrict__ qb,
                                                   bf16* __restrict__ kb,
                                                   bf16* __restrict__ vtb) {
    __shared__ bf16 smem[64*72 + 128*72];
    bf16 (*Ws)[72] = (bf16(*)[72])smem;
    bf16 (*Xs)[72] = (bf16(*)[72])(smem + 64*72);
    int t = threadIdx.x;
    int w = t >> 6, lane = t & 63, quad = lane >> 4, l15 = lane & 15;
    int blk = blockIdx.x;
    int bf = blk % 24, bm = blk / 24;
    int f0 = bf * 64, m0 = bm * 128;

    floatx4 acc[4][2] = {};
    int wrow = t >> 2, wcol = (t & 3) * 16;
    int xrow = t >> 1, xcol = (t & 1) * 32;

    const bf16* wbase = wb + (size_t)(f0 + wrow)*D_MODEL + wcol;
    const bf16* xbase = xb + (size_t)(m0 + xrow)*D_MODEL + xcol;

    // prefetch k-tile 0 into registers
    bf16x8 wp0, wp1, xp0, xp1, xp2, xp3;
    wp0 = *(const bf16x8*)(wbase);
    wp1 = *(const bf16x8*)(wbase + 8);
    xp0 = *(const bf16x8*)(xbase);
    xp1 = *(const bf16x8*)(xbase + 8);
    xp2 = *(const bf16x8*)(xbase + 16);
    xp3 = *(const bf16x8*)(xbase + 24);

    for (int k0 = 0; k0 < D_MODEL; k0 += 64) {
        __syncthreads();
        *(bf16x8*)&Ws[wrow][wcol]    = wp0;
        *(bf16x8*)&Ws[wrow][wcol+8]  = wp1;
        *(bf16x8*)&Xs[xrow][xcol]    = xp0;
        *(bf16x8*)&Xs[xrow][xcol+8]  = xp1;
        *(bf16x8*)&Xs[xrow][xcol+16] = xp2;
        *(bf16x8*)&Xs[xrow][xcol+24] = xp3;
        __syncthreads();

        // prefetch k-tile k0+64 (overlaps the MFMA phase below)
        if (k0 + 64 < D_MODEL) {
            const bf16* wsrc = wbase + k0 + 64;
            wp0 = *(const bf16x8*)(wsrc);
            wp1 = *(const bf16x8*)(wsrc + 8);
            const bf16* xsrc = xbase + k0 + 64;
            xp0 = *(const bf16x8*)(xsrc);
            xp1 = *(const bf16x8*)(xsrc + 8);
            xp2 = *(const bf16x8*)(xsrc + 16);
            xp3 = *(const bf16x8*)(xsrc + 24);
        }

        for (int kf = 0; kf < 2; kf++) {
            bf16x8 af[4], bx[2];
            for (int fi = 0; fi < 4; fi++)
                af[fi] = *(const bf16x8*)&Ws[fi*16 + l15][kf*32 + quad*8];
            for (int mj = 0; mj < 2; mj++)
                bx[mj] = *(const bf16x8*)&Xs[w*32 + mj*16 + l15][kf*32 + quad*8];
            for (int fi = 0; fi < 4; fi++)
                for (int mj = 0; mj < 2; mj++)
                    acc[fi][mj] = __builtin_amdgcn_mfma_f32_16x16x32_bf16(af[fi], bx[mj], acc[fi][mj], 0, 0, 0);
        }
    }

    int mat = f0 >> 9;
    int h = (f0 >> 6) & 7;
    int b = m0 >> 11;
    int nb = m0 & 2047;
    size_t bho = (size_t)(b*NHEAD + h);
    float4 bs4[4];
    for (int fi = 0; fi < 4; fi++)
        bs4[fi] = *(const float4*)(bias + f0 + fi*16 + quad*4);

    if (mat < 2) {
        bf16* dst = (mat == 0) ? qb : kb;
        float sc = (mat == 0) ? 0.125f * LOG2E : 1.0f;
        for (int fi = 0; fi < 4; fi++) {
            for (int mj = 0; mj < 2; mj++) {
                int n = nb + w*32 + mj*16 + l15;
                bf16x4 pv;
                pv[0] = (bf16)((acc[fi][mj][0] + bs4[fi].x) * sc);
                pv[1] = (bf16)((acc[fi][mj][1] + bs4[fi].y) * sc);
                pv[2] = (bf16)((acc[fi][mj][2] + bs4[fi].z) * sc);
                pv[3] = (bf16)((acc[fi][mj][3] + bs4[fi].w) * sc);
                *(bf16x4*)(dst + (bho*NN + n)*HD + fi*16 + quad*4) = pv;
            }
        }
    } else {
        __syncthreads();
        bf16* Vt = smem;                       // [64][136]
        for (int fi = 0; fi < 4; fi++) {
            int d = fi*16 + quad*4;
            for (int mj = 0; mj < 2; mj++) {
                int mlc = w*32 + mj*16 + l15;
                Vt[(d+0)*136 + mlc] = (bf16)(acc[fi][mj][0] + bs4[fi].x);
                Vt[(d+1)*136 + mlc] = (bf16)(acc[fi][mj][1] + bs4[fi].y);
                Vt[(d+2)*136 + mlc] = (bf16)(acc[fi][mj][2] + bs4[fi].z);
                Vt[(d+3)*136 + mlc] = (bf16)(acc[fi][mj][3] + bs4[fi].w);
            }
        }
        __syncthreads();
        int d = t >> 2, mc = (t & 3) * 32;
        bf16* gdst = vtb + (bho*HD + d)*NN + nb + mc;
        for (int c = 0; c < 4; c++)
            *(bf16x8*)(gdst + c*8) = *(const bf16x8*)&Vt[d*136 + mc + c*8];
    }
}

// ---------------- kernel 3: flash attention (r11 best: r8 + s_setprio on MFMA) ----------------
// Cs staged in LDS once, plain block decode, exp2-domain softmax, bitwise-exact
// rescale skip, Ps[64][68], QBLK=64, plain stores, split=2.
__global__ __launch_bounds__(256, 4) void attn(const bf16* __restrict__ qb,
                                               const bf16* __restrict__ kb,
                                               const bf16* __restrict__ vtb,
                                               const float* __restrict__ maskf,
                                               const float* __restrict__ cp,
                                               float* __restrict__ op,
                                               float* __restrict__ ml,
                                               float* __restrict__ out,
                                               int ksplit) {
    __shared__ bf16 Ks[64][72];
    __shared__ bf16 Vts[64][72];
    __shared__ bf16 Ps[64][68];      // stride 34 dwords: conflict-free b64 access
    __shared__ float Cs[2048];
    int t = threadIdx.x;
    int w = t >> 6, lane = t & 63;
    int quad = lane >> 4, l15 = lane & 15;
    int blk = blockIdx.x;
    int bh = blk & 15;
    int rest = blk >> 4;
    int qt = rest & 31, kp = rest >> 5;
    int q0 = qt * 64;
    int nkeys = NN / ksplit;
    int ntiles = nkeys / 64;
    int kbase = kp * nkeys;
    size_t bhoff = (size_t)bh * (NN * HD);

    bf16x8 aq0, aq1;
    {
        const bf16* qp = qb + bhoff + (size_t)(q0 + w*16 + l15)*HD + quad*8;
        aq0 = *(const bf16x8*)(qp);
        aq1 = *(const bf16x8*)(qp + 32);
    }

    float m_i = -1e30f, l_i = 0.f;
    floatx4 o[4] = {};
    int qrow = q0 + w*16 + l15;
    const float* mrow = maskf + (size_t)qrow * NN;
    const float* cpb = cp + (size_t)bh * NN;   // pre-scaled by log2e
    int srow = t >> 2, scol = (t & 3) * 16;

    // stage cp slice once
    for (int i = t; i < nkeys; i += 256) Cs[i] = cpb[kbase + i];

    // prefetch tile 0 K/V
    bf16x8 kr0, kr1, vr0, vr1;
    {
        const bf16* ks = kb + bhoff + (size_t)(kbase + srow)*HD + scol;
        kr0 = *(const bf16x8*)ks; kr1 = *(const bf16x8*)(ks + 8);
        const bf16* vs = vtb + bhoff + (size_t)srow*NN + kbase + scol;
        vr0 = *(const bf16x8*)vs; vr1 = *(const bf16x8*)(vs + 8);
    }
    __syncthreads();   // Cs staged

    float4 bias4[4];
    for (int j = 0; j < 4; j++) {
        float4 mv = *(const float4*)(mrow + kbase + j*16 + quad*4);
        float4 cv = *(const float4*)&Cs[j*16 + quad*4];
        bias4[j].x = fmaf(mv.x, LOG2E, -cv.x);
        bias4[j].y = fmaf(mv.y, LOG2E, -cv.y);
        bias4[j].z = fmaf(mv.z, LOG2E, -cv.z);
        bias4[j].w = fmaf(mv.w, LOG2E, -cv.w);
    }

    for (int kt = 0; kt < ntiles; kt++) {
        __syncthreads();
        *(bf16x8*)&Ks[srow][scol]      = kr0;
        *(bf16x8*)&Ks[srow][scol + 8]  = kr1;
        *(bf16x8*)&Vts[srow][scol]     = vr0;
        *(bf16x8*)&Vts[srow][scol + 8] = vr1;
        __syncthreads();

        // prefetch next tile (global loads overlap compute below)
        float4 mn4[4];
        bool more = (kt + 1 < ntiles);
        if (more) {
            int kn = kbase + (kt+1)*64;
            const bf16* ks = kb + bhoff + (size_t)(kn + srow)*HD + scol;
            kr0 = *(const bf16x8*)ks; kr1 = *(const bf16x8*)(ks + 8);
            const bf16* vs = vtb + bhoff + (size_t)srow*NN + kn + scol;
            vr0 = *(const bf16x8*)vs; vr1 = *(const bf16x8*)(vs + 8);
            for (int j = 0; j < 4; j++)
                mn4[j] = *(const float4*)(mrow + kn + j*16 + quad*4);
        }

        // S^T = K*Q^T + (mask - cp)*log2e, via accumulator init
        floatx4 s[4];
        __builtin_amdgcn_s_setprio(1);
        for (int j = 0; j < 4; j++) {
            s[j][0] = bias4[j].x; s[j][1] = bias4[j].y;
            s[j][2] = bias4[j].z; s[j][3] = bias4[j].w;
            bf16x8 ka0 = *(const bf16x8*)&Ks[j*16 + l15][quad*8];
            bf16x8 ka1 = *(const bf16x8*)&Ks[j*16 + l15][32 + quad*8];
            s[j] = __builtin_amdgcn_mfma_f32_16x16x32_bf16(ka0, aq0, s[j], 0, 0, 0);
            s[j] = __builtin_amdgcn_mfma_f32_16x16x32_bf16(ka1, aq1, s[j], 0, 0, 0);
        }
        __builtin_amdgcn_s_setprio(0);

        // softmax for q=l15; exp2 domain. Balanced max tree (fmax associative: exact)
        float mj0 = fmaxf(fmaxf(fmaxf(s[0][0], s[0][1]), s[0][2]), s[0][3]);
        float mj1 = fmaxf(fmaxf(fmaxf(s[1][0], s[1][1]), s[1][2]), s[1][3]);
        float mj2 = fmaxf(fmaxf(fmaxf(s[2][0], s[2][1]), s[2][2]), s[2][3]);
        float mj3 = fmaxf(fmaxf(fmaxf(s[3][0], s[3][1]), s[3][2]), s[3][3]);
        float mx = fmaxf(fmaxf(mj0, mj1), fmaxf(mj2, mj3));
        mx = fmaxf(mx, __shfl_xor(mx, 16));
        mx = fmaxf(mx, __shfl_xor(mx, 32));

        // exact-skip rescale: if no row's max grew, al==1.0 exactly for every
        // lane -> skipping the rescale is bitwise identical
        if (!__all(mx <= m_i)) {
            float mnew = fmaxf(m_i, mx);
            float al = __builtin_amdgcn_exp2f(m_i - mnew);
            l_i *= al;
            float alc[4];
            for (int r = 0; r < 4; r++) alc[r] = __shfl(al, quad*4 + r);
            for (int dj = 0; dj < 4; dj++)
                for (int r = 0; r < 4; r++) o[dj][r] *= alc[r];
            m_i = mnew;
        }

        // exp2 + sum with 4 independent partials (ILP on the add chain)
        float rsp[4];
        for (int j = 0; j < 4; j++) {
            float p0 = __builtin_amdgcn_exp2f(s[j][0] - m_i);
            float p1 = __builtin_amdgcn_exp2f(s[j][1] - m_i);
            float p2 = __builtin_amdgcn_exp2f(s[j][2] - m_i);
            float p3 = __builtin_amdgcn_exp2f(s[j][3] - m_i);
            s[j][0] = p0; s[j][1] = p1; s[j][2] = p2; s[j][3] = p3;
            rsp[j] = (p0 + p1) + (p2 + p3);
        }
        float rs = (rsp[0] + rsp[1]) + (rsp[2] + rsp[3]);
        rs += __shfl_xor(rs, 16);
        rs += __shfl_xor(rs, 32);
        l_i += rs;

        // P^T -> Ps (b64 writes; same-wave rows, no barrier needed)
        for (int j = 0; j < 4; j++) {
            bf16x4 pv;
            pv[0] = (bf16)s[j][0]; pv[1] = (bf16)s[j][1];
            pv[2] = (bf16)s[j][2]; pv[3] = (bf16)s[j][3];
            *(bf16x4*)&Ps[w*16 + l15][j*16 + quad*4] = pv;
        }

        // O += P*V  (P fragment via two b64 reads: conflict-free at stride 34)
        __builtin_amdgcn_s_setprio(1);
        for (int kf2 = 0; kf2 < 2; kf2++) {
            bf16x4 apl = *(const bf16x4*)&Ps[w*16 + l15][kf2*32 + quad*8];
            bf16x4 aph = *(const bf16x4*)&Ps[w*16 + l15][kf2*32 + quad*8 + 4];
            bf16x8 ap;
            ap[0]=apl[0]; ap[1]=apl[1]; ap[2]=apl[2]; ap[3]=apl[3];
            ap[4]=aph[0]; ap[5]=aph[1]; ap[6]=aph[2]; ap[7]=aph[3];
            for (int dj = 0; dj < 4; dj++) {
                bf16x8 bv = *(const bf16x8*)&Vts[dj*16 + l15][kf2*32 + quad*8];
                o[dj] = __builtin_amdgcn_mfma_f32_16x16x32_bf16(ap, bv, o[dj], 0, 0, 0);
            }
        }
        __builtin_amdgcn_s_setprio(0);

        // rotate next-tile bias: mask from prefetched regs, cp from LDS (short latency)
        if (more) {
            int knl = (kt+1)*64;
            for (int j = 0; j < 4; j++) {
                float4 cv = *(const float4*)&Cs[knl + j*16 + quad*4];
                bias4[j].x = fmaf(mn4[j].x, LOG2E, -cv.x);
                bias4[j].y = fmaf(mn4[j].y, LOG2E, -cv.y);
                bias4[j].z = fmaf(mn4[j].z, LOG2E, -cv.z);
                bias4[j].w = fmaf(mn4[j].w, LOG2E, -cv.w);
            }
        }
    }

    int b = bh >> 3, h = bh & 7;
    if (ksplit == 1) {
        float lc[4];
        for (int r = 0; r < 4; r++) lc[r] = __shfl(l_i, quad*4 + r);
        for (int dj = 0; dj < 4; dj++) {
            for (int r = 0; r < 4; r++) {
                int n = q0 + w*16 + quad*4 + r;
                out[((size_t)(b*NN + n))*D_MODEL + h*HD + dj*16 + l15] = o[dj][r] / lc[r];
            }
        }
    } else {
        size_t pbase = (size_t)kp * BH * NN;
        for (int dj = 0; dj < 4; dj++) {
            for (int r = 0; r < 4; r++) {
                int n = q0 + w*16 + quad*4 + r;
                op[(pbase + bh*NN + n)*HD + dj*16 + l15] = o[dj][r];
            }
        }
        if (quad == 0) {
            float2 v; v.x = m_i; v.y = l_i;
            *(float2*)(ml + (pbase + (size_t)bh*NN + qrow)*2) = v;
        }
    }
}

// ---------------- kernel 4: combine ksplit partials (exp2 domain) ----------------
__global__ __launch_bounds__(256) void combineN(const float* __restrict__ op,
                                                const float* __restrict__ ml,
                                                float* __restrict__ out,
                                                int ksplit) {
    int idx = blockIdx.x * 256 + threadIdx.x;    // 32768 rows * 16 chunks
    int row = idx >> 4, c4 = (idx & 15) * 4;
    float mstar = -1e30f;
    for (int kp = 0; kp < ksplit; kp++)
        mstar = fmaxf(mstar, ml[((size_t)kp*BH*NN + row)*2]);
    float denom = 0.f;
    float ax = 0.f, ay = 0.f, az = 0.f, aw = 0.f;
    for (int kp = 0; kp < ksplit; kp++) {
        float2 m2 = *(const float2*)(ml + ((size_t)kp*BH*NN + row)*2);
        float wgt = __builtin_amdgcn_exp2f(m2.x - mstar);
        denom += wgt * m2.y;
        float4 ov = *(const float4*)(op + ((size_t)kp*BH*NN + row)*HD + c4);
        ax += wgt*ov.x; ay += wgt*ov.y; az += wgt*ov.z; aw += wgt*ov.w;
    }
    float inv = 1.0f / denom;
    int bh = row >> 11, q = row & 2047;
    int b = bh >> 3, h = bh & 7;
    float4 res; res.x = ax*inv; res.y = ay*inv; res.z = az*inv; res.w = aw*inv;
    *(float4*)(out + ((size_t)(b*NN + q))*D_MODEL + h*HD + c4) = res;
}

extern "C" void kernel_launch(void* const* d_in, const int* in_sizes, int n_in,
                              void* d_out, int out_size, void* d_ws, size_t ws_size,
                              hipStream_t stream) {
    const float* x      = (const float*)d_in[0];
    const float* coords = (const float*)d_in[1];
    const float* amask  = (const float*)d_in[2];
    const float* qkv_w  = (const float*)d_in[3];
    const float* qkv_b  = (const float*)d_in[4];
    const float* rw     = (const float*)d_in[5];
    float* out = (float*)d_out;

    char* ws = (char*)d_ws;
    float* cp  = (float*)(ws + 0);          // 131072
    bf16*  xb  = (bf16*) (ws + 131072);     // 4194304
    bf16*  wb  = (bf16*) (ws + 4325376);    // 1572864
    bf16*  qb  = (bf16*) (ws + 5898240);    // 4194304
    bf16*  kb  = (bf16*) (ws + 10092544);   // 4194304
    bf16*  vtb = (bf16*) (ws + 14286848);   // 4194304
    float* op  = (float*)(ws + 18481152);   // split*8388608

    // split=2: halves the op/ml partials roundtrip vs split=4 while keeping
    // exactly 4 attn blocks/CU co-resident (grid 1024 = 256 CU x 4).
    int split = 1;
    if (ws_size >= 35782656u) split = 2;
    float* ml = (float*)(ws + 18481152 + (size_t)split*8388608);

    convxw   <<<dim3(2832), dim3(256), 0, stream>>>(x, qkv_w, coords, rw, xb, wb, cp);
    qkv_gemm <<<dim3(768),  dim3(256), 0, stream>>>(xb, wb, qkv_b, qb, kb, vtb);
    attn     <<<dim3(512*split), dim3(256), 0, stream>>>(qb, kb, vtb, amask, cp, op, ml, out, split);
    if (split > 1)
        combineN<<<dim3(2048), dim3(256), 0, stream>>>(op, ml, out, split);
}

// Round 13
// 145.763 us; speedup vs baseline: 1.0122x; 1.0122x over previous
//
#include <hip/hip_runtime.h>
#include <hip/hip_bf16.h>

typedef __bf16 bf16;
typedef __bf16 bf16x4 __attribute__((ext_vector_type(4)));
typedef __bf16 bf16x8 __attribute__((ext_vector_type(8)));
typedef float floatx4 __attribute__((ext_vector_type(4)));

#define D_MODEL 512
#define NHEAD 8
#define HD 64
#define NB 2
#define NN 2048
#define BH (NB*NHEAD)
#define LOG2E 1.4426950408889634f

// ---------------- kernel 0: convert x,w fp32 -> bf16; fused coord projection ----------------
__global__ __launch_bounds__(256) void convxw(const float* __restrict__ x,
                                              const float* __restrict__ w,
                                              const float* __restrict__ coords,
                                              const float* __restrict__ rw,
                                              bf16* __restrict__ xb,
                                              bf16* __restrict__ wb,
                                              float* __restrict__ cp) {
    int bid = blockIdx.x;
    if (bid >= 2816) {
        // coordproj tail: 16 blocks, cp pre-scaled by log2(e) for exp2-domain softmax
        int idx = (bid - 2816) * 256 + threadIdx.x;
        int b = idx >> 11, n = idx & 2047;
        float c0 = coords[idx*3 + 0];
        float c1 = coords[idx*3 + 1];
        float c2 = coords[idx*3 + 2];
        for (int h = 0; h < NHEAD; h++) {
            float v = c0*rw[h*3+0] + c1*rw[h*3+1] + c2*rw[h*3+2];
            cp[(size_t)(b*NHEAD + h)*NN + n] = v * LOG2E;
        }
        return;
    }
    int idx = bid * 256 + threadIdx.x;
    const float* src; bf16* dst; int i4;
    if (idx < 524288) { src = x; dst = xb; i4 = idx; }
    else              { src = w; dst = wb; i4 = idx - 524288; }
    float4 v = *(const float4*)(src + (size_t)i4*4);
    bf16x4 o; o[0] = (bf16)v.x; o[1] = (bf16)v.y; o[2] = (bf16)v.z; o[3] = (bf16)v.w;
    *(bf16x4*)(dst + (size_t)i4*4) = o;
}

// ---------------- kernel 2: QKV GEMM, C^T = W * X^T (bf16 inputs) ----------------
// Tile: 64 features x 128 rows, K=512. 768 blocks, 256 thr / 4 waves.
// amdgpu_waves_per_eu(4,5): LDS caps this kernel at 5 blocks/CU anyway, so
// let the allocator use ~128 VGPRs and keep the k-tile register prefetch LIVE
// (at the default 8-waves/EU target it was sinking the prefetch to use points).
__global__ __attribute__((amdgpu_waves_per_eu(4, 5)))
__launch_bounds__(256) void qkv_gemm(const bf16* __restrict__ xb,
                                     const bf16* __restrict__ wb,
                                     const float* __restrict__ bias,
                                     bf16* __restrict__ qb,
                                     bf16* __restrict__ kb,
                                     bf16* __restrict__ vtb) {
    __shared__ bf16 smem[64*72 + 128*72];
    bf16 (*Ws)[72] = (bf16(*)[72])smem;
    bf16 (*Xs)[72] = (bf16(*)[72])(smem + 64*72);
    int t = threadIdx.x;
    int w = t >> 6, lane = t & 63, quad = lane >> 4, l15 = lane & 15;
    int blk = blockIdx.x;
    int bf = blk % 24, bm = blk / 24;
    int f0 = bf * 64, m0 = bm * 128;

    floatx4 acc[4][2] = {};
    int wrow = t >> 2, wcol = (t & 3) * 16;
    int xrow = t >> 1, xcol = (t & 1) * 32;

    const bf16* wbase = wb + (size_t)(f0 + wrow)*D_MODEL + wcol;
    const bf16* xbase = xb + (size_t)(m0 + xrow)*D_MODEL + xcol;

    // prefetch k-tile 0 into registers
    bf16x8 wp0, wp1, xp0, xp1, xp2, xp3;
    wp0 = *(const bf16x8*)(wbase);
    wp1 = *(const bf16x8*)(wbase + 8);
    xp0 = *(const bf16x8*)(xbase);
    xp1 = *(const bf16x8*)(xbase + 8);
    xp2 = *(const bf16x8*)(xbase + 16);
    xp3 = *(const bf16x8*)(xbase + 24);

    for (int k0 = 0; k0 < D_MODEL; k0 += 64) {
        __syncthreads();
        *(bf16x8*)&Ws[wrow][wcol]    = wp0;
        *(bf16x8*)&Ws[wrow][wcol+8]  = wp1;
        *(bf16x8*)&Xs[xrow][xcol]    = xp0;
        *(bf16x8*)&Xs[xrow][xcol+8]  = xp1;
        *(bf16x8*)&Xs[xrow][xcol+16] = xp2;
        *(bf16x8*)&Xs[xrow][xcol+24] = xp3;
        __syncthreads();

        // prefetch k-tile k0+64 (overlaps the MFMA phase below)
        if (k0 + 64 < D_MODEL) {
            const bf16* wsrc = wbase + k0 + 64;
            wp0 = *(const bf16x8*)(wsrc);
            wp1 = *(const bf16x8*)(wsrc + 8);
            const bf16* xsrc = xbase + k0 + 64;
            xp0 = *(const bf16x8*)(xsrc);
            xp1 = *(const bf16x8*)(xsrc + 8);
            xp2 = *(const bf16x8*)(xsrc + 16);
            xp3 = *(const bf16x8*)(xsrc + 24);
        }

        for (int kf = 0; kf < 2; kf++) {
            bf16x8 af[4], bx[2];
            for (int fi = 0; fi < 4; fi++)
                af[fi] = *(const bf16x8*)&Ws[fi*16 + l15][kf*32 + quad*8];
            for (int mj = 0; mj < 2; mj++)
                bx[mj] = *(const bf16x8*)&Xs[w*32 + mj*16 + l15][kf*32 + quad*8];
            for (int fi = 0; fi < 4; fi++)
                for (int mj = 0; mj < 2; mj++)
                    acc[fi][mj] = __builtin_amdgcn_mfma_f32_16x16x32_bf16(af[fi], bx[mj], acc[fi][mj], 0, 0, 0);
        }
    }

    int mat = f0 >> 9;
    int h = (f0 >> 6) & 7;
    int b = m0 >> 11;
    int nb = m0 & 2047;
    size_t bho = (size_t)(b*NHEAD + h);
    float4 bs4[4];
    for (int fi = 0; fi < 4; fi++)
        bs4[fi] = *(const float4*)(bias + f0 + fi*16 + quad*4);

    if (mat < 2) {
        bf16* dst = (mat == 0) ? qb : kb;
        float sc = (mat == 0) ? 0.125f * LOG2E : 1.0f;
        for (int fi = 0; fi < 4; fi++) {
            for (int mj = 0; mj < 2; mj++) {
                int n = nb + w*32 + mj*16 + l15;
                bf16x4 pv;
                pv[0] = (bf16)((acc[fi][mj][0] + bs4[fi].x) * sc);
                pv[1] = (bf16)((acc[fi][mj][1] + bs4[fi].y) * sc);
                pv[2] = (bf16)((acc[fi][mj][2] + bs4[fi].z) * sc);
                pv[3] = (bf16)((acc[fi][mj][3] + bs4[fi].w) * sc);
                *(bf16x4*)(dst + (bho*NN + n)*HD + fi*16 + quad*4) = pv;
            }
        }
    } else {
        __syncthreads();
        bf16* Vt = smem;                       // [64][136]
        for (int fi = 0; fi < 4; fi++) {
            int d = fi*16 + quad*4;
            for (int mj = 0; mj < 2; mj++) {
                int mlc = w*32 + mj*16 + l15;
                Vt[(d+0)*136 + mlc] = (bf16)(acc[fi][mj][0] + bs4[fi].x);
                Vt[(d+1)*136 + mlc] = (bf16)(acc[fi][mj][1] + bs4[fi].y);
                Vt[(d+2)*136 + mlc] = (bf16)(acc[fi][mj][2] + bs4[fi].z);
                Vt[(d+3)*136 + mlc] = (bf16)(acc[fi][mj][3] + bs4[fi].w);
            }
        }
        __syncthreads();
        int d = t >> 2, mc = (t & 3) * 32;
        bf16* gdst = vtb + (bho*HD + d)*NN + nb + mc;
        for (int c = 0; c < 4; c++)
            *(bf16x8*)(gdst + c*8) = *(const bf16x8*)&Vt[d*136 + mc + c*8];
    }
}

// ---------------- kernel 3: flash attention (r11 structure + waves_per_eu(4,4)) ----------------
// LDS (35328 B) caps occupancy at 4 blocks/CU = 4 waves/EU regardless of VGPRs,
// so pin waves_per_eu(4,4): allocator budget rises 64 -> 128 VGPR and the
// K/V/mask register prefetch stays LIVE across the compute phase instead of
// being sunk to its use points (the r3/r12 VGPR=64 signature).
// Cs staged in LDS once, plain block decode, exp2-domain softmax, bitwise-exact
// rescale skip, Ps[64][68], QBLK=64, plain stores, split=2, setprio on MFMA.
__global__ __attribute__((amdgpu_waves_per_eu(4, 4)))
__launch_bounds__(256) void attn(const bf16* __restrict__ qb,
                                 const bf16* __restrict__ kb,
                                 const bf16* __restrict__ vtb,
                                 const float* __restrict__ maskf,
                                 const float* __restrict__ cp,
                                 float* __restrict__ op,
                                 float* __restrict__ ml,
                                 float* __restrict__ out,
                                 int ksplit) {
    __shared__ bf16 Ks[64][72];
    __shared__ bf16 Vts[64][72];
    __shared__ bf16 Ps[64][68];      // stride 34 dwords: conflict-free b64 access
    __shared__ float Cs[2048];
    int t = threadIdx.x;
    int w = t >> 6, lane = t & 63;
    int quad = lane >> 4, l15 = lane & 15;
    int blk = blockIdx.x;
    int bh = blk & 15;
    int rest = blk >> 4;
    int qt = rest & 31, kp = rest >> 5;
    int q0 = qt * 64;
    int nkeys = NN / ksplit;
    int ntiles = nkeys / 64;
    int kbase = kp * nkeys;
    size_t bhoff = (size_t)bh * (NN * HD);

    bf16x8 aq0, aq1;
    {
        const bf16* qp = qb + bhoff + (size_t)(q0 + w*16 + l15)*HD + quad*8;
        aq0 = *(const bf16x8*)(qp);
        aq1 = *(const bf16x8*)(qp + 32);
    }

    float m_i = -1e30f, l_i = 0.f;
    floatx4 o[4] = {};
    int qrow = q0 + w*16 + l15;
    const float* mrow = maskf + (size_t)qrow * NN;
    const float* cpb = cp + (size_t)bh * NN;   // pre-scaled by log2e
    int srow = t >> 2, scol = (t & 3) * 16;

    // stage cp slice once
    for (int i = t; i < nkeys; i += 256) Cs[i] = cpb[kbase + i];

    // prefetch tile 0 K/V
    bf16x8 kr0, kr1, vr0, vr1;
    {
        const bf16* ks = kb + bhoff + (size_t)(kbase + srow)*HD + scol;
        kr0 = *(const bf16x8*)ks; kr1 = *(const bf16x8*)(ks + 8);
        const bf16* vs = vtb + bhoff + (size_t)srow*NN + kbase + scol;
        vr0 = *(const bf16x8*)vs; vr1 = *(const bf16x8*)(vs + 8);
    }
    __syncthreads();   // Cs staged

    float4 bias4[4];
    for (int j = 0; j < 4; j++) {
        float4 mv = *(const float4*)(mrow + kbase + j*16 + quad*4);
        float4 cv = *(const float4*)&Cs[j*16 + quad*4];
        bias4[j].x = fmaf(mv.x, LOG2E, -cv.x);
        bias4[j].y = fmaf(mv.y, LOG2E, -cv.y);
        bias4[j].z = fmaf(mv.z, LOG2E, -cv.z);
        bias4[j].w = fmaf(mv.w, LOG2E, -cv.w);
    }

    for (int kt = 0; kt < ntiles; kt++) {
        __syncthreads();
        *(bf16x8*)&Ks[srow][scol]      = kr0;
        *(bf16x8*)&Ks[srow][scol + 8]  = kr1;
        *(bf16x8*)&Vts[srow][scol]     = vr0;
        *(bf16x8*)&Vts[srow][scol + 8] = vr1;
        __syncthreads();

        // prefetch next tile (global loads overlap compute below)
        float4 mn4[4];
        bool more = (kt + 1 < ntiles);
        if (more) {
            int kn = kbase + (kt+1)*64;
            const bf16* ks = kb + bhoff + (size_t)(kn + srow)*HD + scol;
            kr0 = *(const bf16x8*)ks; kr1 = *(const bf16x8*)(ks + 8);
            const bf16* vs = vtb + bhoff + (size_t)srow*NN + kn + scol;
            vr0 = *(const bf16x8*)vs; vr1 = *(const bf16x8*)(vs + 8);
            for (int j = 0; j < 4; j++)
                mn4[j] = *(const float4*)(mrow + kn + j*16 + quad*4);
        }

        // S^T = K*Q^T + (mask - cp)*log2e, via accumulator init
        floatx4 s[4];
        __builtin_amdgcn_s_setprio(1);
        for (int j = 0; j < 4; j++) {
            s[j][0] = bias4[j].x; s[j][1] = bias4[j].y;
            s[j][2] = bias4[j].z; s[j][3] = bias4[j].w;
            bf16x8 ka0 = *(const bf16x8*)&Ks[j*16 + l15][quad*8];
            bf16x8 ka1 = *(const bf16x8*)&Ks[j*16 + l15][32 + quad*8];
            s[j] = __builtin_amdgcn_mfma_f32_16x16x32_bf16(ka0, aq0, s[j], 0, 0, 0);
            s[j] = __builtin_amdgcn_mfma_f32_16x16x32_bf16(ka1, aq1, s[j], 0, 0, 0);
        }
        __builtin_amdgcn_s_setprio(0);

        // softmax for q=l15; exp2 domain. Balanced max tree (fmax associative: exact)
        float mj0 = fmaxf(fmaxf(fmaxf(s[0][0], s[0][1]), s[0][2]), s[0][3]);
        float mj1 = fmaxf(fmaxf(fmaxf(s[1][0], s[1][1]), s[1][2]), s[1][3]);
        float mj2 = fmaxf(fmaxf(fmaxf(s[2][0], s[2][1]), s[2][2]), s[2][3]);
        float mj3 = fmaxf(fmaxf(fmaxf(s[3][0], s[3][1]), s[3][2]), s[3][3]);
        float mx = fmaxf(fmaxf(mj0, mj1), fmaxf(mj2, mj3));
        mx = fmaxf(mx, __shfl_xor(mx, 16));
        mx = fmaxf(mx, __shfl_xor(mx, 32));

        // exact-skip rescale: if no row's max grew, al==1.0 exactly for every
        // lane -> skipping the rescale is bitwise identical
        if (!__all(mx <= m_i)) {
            float mnew = fmaxf(m_i, mx);
            float al = __builtin_amdgcn_exp2f(m_i - mnew);
            l_i *= al;
            float alc[4];
            for (int r = 0; r < 4; r++) alc[r] = __shfl(al, quad*4 + r);
            for (int dj = 0; dj < 4; dj++)
                for (int r = 0; r < 4; r++) o[dj][r] *= alc[r];
            m_i = mnew;
        }

        // exp2 + sum with 4 independent partials (ILP on the add chain)
        float rsp[4];
        for (int j = 0; j < 4; j++) {
            float p0 = __builtin_amdgcn_exp2f(s[j][0] - m_i);
            float p1 = __builtin_amdgcn_exp2f(s[j][1] - m_i);
            float p2 = __builtin_amdgcn_exp2f(s[j][2] - m_i);
            float p3 = __builtin_amdgcn_exp2f(s[j][3] - m_i);
            s[j][0] = p0; s[j][1] = p1; s[j][2] = p2; s[j][3] = p3;
            rsp[j] = (p0 + p1) + (p2 + p3);
        }
        float rs = (rsp[0] + rsp[1]) + (rsp[2] + rsp[3]);
        rs += __shfl_xor(rs, 16);
        rs += __shfl_xor(rs, 32);
        l_i += rs;

        // P^T -> Ps (b64 writes; same-wave rows, no barrier needed)
        for (int j = 0; j < 4; j++) {
            bf16x4 pv;
            pv[0] = (bf16)s[j][0]; pv[1] = (bf16)s[j][1];
            pv[2] = (bf16)s[j][2]; pv[3] = (bf16)s[j][3];
            *(bf16x4*)&Ps[w*16 + l15][j*16 + quad*4] = pv;
        }

        // O += P*V  (P fragment via two b64 reads: conflict-free at stride 34)
        __builtin_amdgcn_s_setprio(1);
        for (int kf2 = 0; kf2 < 2; kf2++) {
            bf16x4 apl = *(const bf16x4*)&Ps[w*16 + l15][kf2*32 + quad*8];
            bf16x4 aph = *(const bf16x4*)&Ps[w*16 + l15][kf2*32 + quad*8 + 4];
            bf16x8 ap;
            ap[0]=apl[0]; ap[1]=apl[1]; ap[2]=apl[2]; ap[3]=apl[3];
            ap[4]=aph[0]; ap[5]=aph[1]; ap[6]=aph[2]; ap[7]=aph[3];
            for (int dj = 0; dj < 4; dj++) {
                bf16x8 bv = *(const bf16x8*)&Vts[dj*16 + l15][kf2*32 + quad*8];
                o[dj] = __builtin_amdgcn_mfma_f32_16x16x32_bf16(ap, bv, o[dj], 0, 0, 0);
            }
        }
        __builtin_amdgcn_s_setprio(0);

        // rotate next-tile bias: mask from prefetched regs, cp from LDS (short latency)
        if (more) {
            int knl = (kt+1)*64;
            for (int j = 0; j < 4; j++) {
                float4 cv = *(const float4*)&Cs[knl + j*16 + quad*4];
                bias4[j].x = fmaf(mn4[j].x, LOG2E, -cv.x);
                bias4[j].y = fmaf(mn4[j].y, LOG2E, -cv.y);
                bias4[j].z = fmaf(mn4[j].z, LOG2E, -cv.z);
                bias4[j].w = fmaf(mn4[j].w, LOG2E, -cv.w);
            }
        }
    }

    int b = bh >> 3, h = bh & 7;
    if (ksplit == 1) {
        float lc[4];
        for (int r = 0; r < 4; r++) lc[r] = __shfl(l_i, quad*4 + r);
        for (int dj = 0; dj < 4; dj++) {
            for (int r = 0; r < 4; r++) {
                int n = q0 + w*16 + quad*4 + r;
                out[((size_t)(b*NN + n))*D_MODEL + h*HD + dj*16 + l15] = o[dj][r] / lc[r];
            }
        }
    } else {
        size_t pbase = (size_t)kp * BH * NN;
        for (int dj = 0; dj < 4; dj++) {
            for (int r = 0; r < 4; r++) {
                int n = q0 + w*16 + quad*4 + r;
                op[(pbase + bh*NN + n)*HD + dj*16 + l15] = o[dj][r];
            }
        }
        if (quad == 0) {
            float2 v; v.x = m_i; v.y = l_i;
            *(float2*)(ml + (pbase + (size_t)bh*NN + qrow)*2) = v;
        }
    }
}

// ---------------- kernel 4: combine ksplit partials (exp2 domain) ----------------
__global__ __launch_bounds__(256) void combineN(const float* __restrict__ op,
                                                const float* __restrict__ ml,
                                                float* __restrict__ out,
                                                int ksplit) {
    int idx = blockIdx.x * 256 + threadIdx.x;    // 32768 rows * 16 chunks
    int row = idx >> 4, c4 = (idx & 15) * 4;
    float mstar = -1e30f;
    for (int kp = 0; kp < ksplit; kp++)
        mstar = fmaxf(mstar, ml[((size_t)kp*BH*NN + row)*2]);
    float denom = 0.f;
    float ax = 0.f, ay = 0.f, az = 0.f, aw = 0.f;
    for (int kp = 0; kp < ksplit; kp++) {
        float2 m2 = *(const float2*)(ml + ((size_t)kp*BH*NN + row)*2);
        float wgt = __builtin_amdgcn_exp2f(m2.x - mstar);
        denom += wgt * m2.y;
        float4 ov = *(const float4*)(op + ((size_t)kp*BH*NN + row)*HD + c4);
        ax += wgt*ov.x; ay += wgt*ov.y; az += wgt*ov.z; aw += wgt*ov.w;
    }
    float inv = 1.0f / denom;
    int bh = row >> 11, q = row & 2047;
    int b = bh >> 3, h = bh & 7;
    float4 res; res.x = ax*inv; res.y = ay*inv; res.z = az*inv; res.w = aw*inv;
    *(float4*)(out + ((size_t)(b*NN + q))*D_MODEL + h*HD + c4) = res;
}

extern "C" void kernel_launch(void* const* d_in, const int* in_sizes, int n_in,
                              void* d_out, int out_size, void* d_ws, size_t ws_size,
                              hipStream_t stream) {
    const float* x      = (const float*)d_in[0];
    const float* coords = (const float*)d_in[1];
    const float* amask  = (const float*)d_in[2];
    const float* qkv_w  = (const float*)d_in[3];
    const float* qkv_b  = (const float*)d_in[4];
    const float* rw     = (const float*)d_in[5];
    float* out = (float*)d_out;

    char* ws = (char*)d_ws;
    float* cp  = (float*)(ws + 0);          // 131072
    bf16*  xb  = (bf16*) (ws + 131072);     // 4194304
    bf16*  wb  = (bf16*) (ws + 4325376);    // 1572864
    bf16*  qb  = (bf16*) (ws + 5898240);    // 4194304
    bf16*  kb  = (bf16*) (ws + 10092544);   // 4194304
    bf16*  vtb = (bf16*) (ws + 14286848);   // 4194304
    float* op  = (float*)(ws + 18481152);   // split*8388608

    // split=2: halves the op/ml partials roundtrip vs split=4 while keeping
    // exactly 4 attn blocks/CU co-resident (grid 1024 = 256 CU x 4).
    int split = 1;
    if (ws_size >= 35782656u) split = 2;
    float* ml = (float*)(ws + 18481152 + (size_t)split*8388608);

    convxw   <<<dim3(2832), dim3(256), 0, stream>>>(x, qkv_w, coords, rw, xb, wb, cp);
    qkv_gemm <<<dim3(768),  dim3(256), 0, stream>>>(xb, wb, qkv_b, qb, kb, vtb);
    attn     <<<dim3(512*split), dim3(256), 0, stream>>>(qb, kb, vtb, amask, cp, op, ml, out, split);
    if (split > 1)
        combineN<<<dim3(2048), dim3(256), 0, stream>>>(op, ml, out, split);
}

// Round 14
// 143.707 us; speedup vs baseline: 1.0267x; 1.0143x over previous
//
#include <hip/hip_runtime.h>
#include <hip/hip_bf16.h>

typedef __bf16 bf16;
typedef __bf16 bf16x4 __attribute__((ext_vector_type(4)));
typedef __bf16 bf16x8 __attribute__((ext_vector_type(8)));
typedef float floatx4 __attribute__((ext_vector_type(4)));

#define D_MODEL 512
#define NHEAD 8
#define HD 64
#define NB 2
#define NN 2048
#define BH (NB*NHEAD)
#define LOG2E 1.4426950408889634f

// address-space typedefs for global_load_lds
typedef __attribute__((address_space(1))) void gas_void;
typedef __attribute__((address_space(3))) void las_void;

// async 16B global->LDS: lds dest is wave-uniform base + lane*16 (linear!)
static __device__ __forceinline__ void gload_lds16(const bf16* g, bf16* l) {
    __builtin_amdgcn_global_load_lds((gas_void*)g, (las_void*)l, 16, 0, 0);
}

// ---------------- kernel 0: convert x,w fp32 -> bf16; fused coord projection ----------------
__global__ __launch_bounds__(256) void convxw(const float* __restrict__ x,
                                              const float* __restrict__ w,
                                              const float* __restrict__ coords,
                                              const float* __restrict__ rw,
                                              bf16* __restrict__ xb,
                                              bf16* __restrict__ wb,
                                              float* __restrict__ cp) {
    int bid = blockIdx.x;
    if (bid >= 2816) {
        // coordproj tail: 16 blocks, cp pre-scaled by log2(e) for exp2-domain softmax
        int idx = (bid - 2816) * 256 + threadIdx.x;
        int b = idx >> 11, n = idx & 2047;
        float c0 = coords[idx*3 + 0];
        float c1 = coords[idx*3 + 1];
        float c2 = coords[idx*3 + 2];
        for (int h = 0; h < NHEAD; h++) {
            float v = c0*rw[h*3+0] + c1*rw[h*3+1] + c2*rw[h*3+2];
            cp[(size_t)(b*NHEAD + h)*NN + n] = v * LOG2E;
        }
        return;
    }
    int idx = bid * 256 + threadIdx.x;
    const float* src; bf16* dst; int i4;
    if (idx < 524288) { src = x; dst = xb; i4 = idx; }
    else              { src = w; dst = wb; i4 = idx - 524288; }
    float4 v = *(const float4*)(src + (size_t)i4*4);
    bf16x4 o; o[0] = (bf16)v.x; o[1] = (bf16)v.y; o[2] = (bf16)v.z; o[3] = (bf16)v.w;
    *(bf16x4*)(dst + (size_t)i4*4) = o;
}

// ---------------- kernel 2: QKV GEMM, C^T = W * X^T (bf16 inputs) ----------------
// Tile: 64 features x 128 rows, K=512. 768 blocks, 256 thr / 4 waves.
// Staging via async global_load_lds width=16 (m97 lever): linear LDS dest,
// pre-swizzled GLOBAL source col (gcol = lcol ^ ((row&7)*8)), matching XOR on
// fragment reads. Unpadded [.][64] tiles; swizzled reads hit the b128 BW floor
// (8 slots), same as the old padded layout, but staging has no VGPR roundtrip.
__global__ __launch_bounds__(256, 4) void qkv_gemm(const bf16* __restrict__ xb,
                                                   const bf16* __restrict__ wb,
                                                   const float* __restrict__ bias,
                                                   bf16* __restrict__ qb,
                                                   bf16* __restrict__ kb,
                                                   bf16* __restrict__ vtb) {
    __shared__ bf16 smem[64*64 + 128*64];   // 24576 B
    bf16* WsL = smem;            // [64][64]  swizzled storage
    bf16* XsL = smem + 64*64;    // [128][64] swizzled storage
    int t = threadIdx.x;
    int w = t >> 6, lane = t & 63, quad = lane >> 4, l15 = lane & 15;
    int blk = blockIdx.x;
    int bf = blk % 24, bm = blk / 24;
    int f0 = bf * 64, m0 = bm * 128;

    floatx4 acc[4][2] = {};

    int lrow = lane >> 3;                 // 0..7  (row within 8-row group)
    int lcol = (lane & 7) * 8;            // 0,8,..,56 (bf16 col chunk)
    int gcol = lcol ^ (lrow * 8);         // pre-swizzled global source col
    int swz15 = (l15 & 7) * 8;            // read-side XOR term (row&7 == l15&7)

    for (int k0 = 0; k0 < D_MODEL; k0 += 64) {
        __syncthreads();
        // async stage: wave w covers W rows [w*16, w*16+16) and X rows [w*32, w*32+32)
        for (int i = 0; i < 2; i++) {
            int r0 = w*16 + i*8;
            gload_lds16(wb + (size_t)(f0 + r0 + lrow)*D_MODEL + k0 + gcol, WsL + r0*64);
        }
        for (int i = 0; i < 4; i++) {
            int r0 = w*32 + i*8;
            gload_lds16(xb + (size_t)(m0 + r0 + lrow)*D_MODEL + k0 + gcol, XsL + r0*64);
        }
        __syncthreads();   // compiler drains vmcnt(0) before barrier: tiles landed

        for (int kf = 0; kf < 2; kf++) {
            int csw = (kf*32) ^ 0;   // base; full col = (kf*32 + quad*8) ^ swz15
            bf16x8 af[4], bx[2];
            for (int fi = 0; fi < 4; fi++)
                af[fi] = *(const bf16x8*)&WsL[(fi*16 + l15)*64 + (((kf*32 + quad*8)) ^ swz15)];
            for (int mj = 0; mj < 2; mj++)
                bx[mj] = *(const bf16x8*)&XsL[(w*32 + mj*16 + l15)*64 + (((kf*32 + quad*8)) ^ swz15)];
            (void)csw;
            for (int fi = 0; fi < 4; fi++)
                for (int mj = 0; mj < 2; mj++)
                    acc[fi][mj] = __builtin_amdgcn_mfma_f32_16x16x32_bf16(af[fi], bx[mj], acc[fi][mj], 0, 0, 0);
        }
    }

    int mat = f0 >> 9;
    int h = (f0 >> 6) & 7;
    int b = m0 >> 11;
    int nb = m0 & 2047;
    size_t bho = (size_t)(b*NHEAD + h);
    float4 bs4[4];
    for (int fi = 0; fi < 4; fi++)
        bs4[fi] = *(const float4*)(bias + f0 + fi*16 + quad*4);

    if (mat < 2) {
        bf16* dst = (mat == 0) ? qb : kb;
        float sc = (mat == 0) ? 0.125f * LOG2E : 1.0f;
        for (int fi = 0; fi < 4; fi++) {
            for (int mj = 0; mj < 2; mj++) {
                int n = nb + w*32 + mj*16 + l15;
                bf16x4 pv;
                pv[0] = (bf16)((acc[fi][mj][0] + bs4[fi].x) * sc);
                pv[1] = (bf16)((acc[fi][mj][1] + bs4[fi].y) * sc);
                pv[2] = (bf16)((acc[fi][mj][2] + bs4[fi].z) * sc);
                pv[3] = (bf16)((acc[fi][mj][3] + bs4[fi].w) * sc);
                *(bf16x4*)(dst + (bho*NN + n)*HD + fi*16 + quad*4) = pv;
            }
        }
    } else {
        __syncthreads();
        bf16* Vt = smem;                       // [64][136], 8704 bf16 <= 12288
        for (int fi = 0; fi < 4; fi++) {
            int d = fi*16 + quad*4;
            for (int mj = 0; mj < 2; mj++) {
                int mlc = w*32 + mj*16 + l15;
                Vt[(d+0)*136 + mlc] = (bf16)(acc[fi][mj][0] + bs4[fi].x);
                Vt[(d+1)*136 + mlc] = (bf16)(acc[fi][mj][1] + bs4[fi].y);
                Vt[(d+2)*136 + mlc] = (bf16)(acc[fi][mj][2] + bs4[fi].z);
                Vt[(d+3)*136 + mlc] = (bf16)(acc[fi][mj][3] + bs4[fi].w);
            }
        }
        __syncthreads();
        int d = t >> 2, mc = (t & 3) * 32;
        bf16* gdst = vtb + (bho*HD + d)*NN + nb + mc;
        for (int c = 0; c < 4; c++)
            *(bf16x8*)(gdst + c*8) = *(const bf16x8*)&Vt[d*136 + mc + c*8];
    }
}

// ---------------- kernel 3: flash attention (r13 best, unchanged) ----------------
__global__ __attribute__((amdgpu_waves_per_eu(4, 4)))
__launch_bounds__(256) void attn(const bf16* __restrict__ qb,
                                 const bf16* __restrict__ kb,
                                 const bf16* __restrict__ vtb,
                                 const float* __restrict__ maskf,
                                 const float* __restrict__ cp,
                                 float* __restrict__ op,
                                 float* __restrict__ ml,
                                 float* __restrict__ out,
                                 int ksplit) {
    __shared__ bf16 Ks[64][72];
    __shared__ bf16 Vts[64][72];
    __shared__ bf16 Ps[64][68];      // stride 34 dwords: conflict-free b64 access
    __shared__ float Cs[2048];
    int t = threadIdx.x;
    int w = t >> 6, lane = t & 63;
    int quad = lane >> 4, l15 = lane & 15;
    int blk = blockIdx.x;
    int bh = blk & 15;
    int rest = blk >> 4;
    int qt = rest & 31, kp = rest >> 5;
    int q0 = qt * 64;
    int nkeys = NN / ksplit;
    int ntiles = nkeys / 64;
    int kbase = kp * nkeys;
    size_t bhoff = (size_t)bh * (NN * HD);

    bf16x8 aq0, aq1;
    {
        const bf16* qp = qb + bhoff + (size_t)(q0 + w*16 + l15)*HD + quad*8;
        aq0 = *(const bf16x8*)(qp);
        aq1 = *(const bf16x8*)(qp + 32);
    }

    float m_i = -1e30f, l_i = 0.f;
    floatx4 o[4] = {};
    int qrow = q0 + w*16 + l15;
    const float* mrow = maskf + (size_t)qrow * NN;
    const float* cpb = cp + (size_t)bh * NN;   // pre-scaled by log2e
    int srow = t >> 2, scol = (t & 3) * 16;

    // stage cp slice once
    for (int i = t; i < nkeys; i += 256) Cs[i] = cpb[kbase + i];

    // prefetch tile 0 K/V
    bf16x8 kr0, kr1, vr0, vr1;
    {
        const bf16* ks = kb + bhoff + (size_t)(kbase + srow)*HD + scol;
        kr0 = *(const bf16x8*)ks; kr1 = *(const bf16x8*)(ks + 8);
        const bf16* vs = vtb + bhoff + (size_t)srow*NN + kbase + scol;
        vr0 = *(const bf16x8*)vs; vr1 = *(const bf16x8*)(vs + 8);
    }
    __syncthreads();   // Cs staged

    float4 bias4[4];
    for (int j = 0; j < 4; j++) {
        float4 mv = *(const float4*)(mrow + kbase + j*16 + quad*4);
        float4 cv = *(const float4*)&Cs[j*16 + quad*4];
        bias4[j].x = fmaf(mv.x, LOG2E, -cv.x);
        bias4[j].y = fmaf(mv.y, LOG2E, -cv.y);
        bias4[j].z = fmaf(mv.z, LOG2E, -cv.z);
        bias4[j].w = fmaf(mv.w, LOG2E, -cv.w);
    }

    for (int kt = 0; kt < ntiles; kt++) {
        __syncthreads();
        *(bf16x8*)&Ks[srow][scol]      = kr0;
        *(bf16x8*)&Ks[srow][scol + 8]  = kr1;
        *(bf16x8*)&Vts[srow][scol]     = vr0;
        *(bf16x8*)&Vts[srow][scol + 8] = vr1;
        __syncthreads();

        // prefetch next tile (global loads overlap compute below)
        float4 mn4[4];
        bool more = (kt + 1 < ntiles);
        if (more) {
            int kn = kbase + (kt+1)*64;
            const bf16* ks = kb + bhoff + (size_t)(kn + srow)*HD + scol;
            kr0 = *(const bf16x8*)ks; kr1 = *(const bf16x8*)(ks + 8);
            const bf16* vs = vtb + bhoff + (size_t)srow*NN + kn + scol;
            vr0 = *(const bf16x8*)vs; vr1 = *(const bf16x8*)(vs + 8);
            for (int j = 0; j < 4; j++)
                mn4[j] = *(const float4*)(mrow + kn + j*16 + quad*4);
        }

        // S^T = K*Q^T + (mask - cp)*log2e, via accumulator init
        floatx4 s[4];
        __builtin_amdgcn_s_setprio(1);
        for (int j = 0; j < 4; j++) {
            s[j][0] = bias4[j].x; s[j][1] = bias4[j].y;
            s[j][2] = bias4[j].z; s[j][3] = bias4[j].w;
            bf16x8 ka0 = *(const bf16x8*)&Ks[j*16 + l15][quad*8];
            bf16x8 ka1 = *(const bf16x8*)&Ks[j*16 + l15][32 + quad*8];
            s[j] = __builtin_amdgcn_mfma_f32_16x16x32_bf16(ka0, aq0, s[j], 0, 0, 0);
            s[j] = __builtin_amdgcn_mfma_f32_16x16x32_bf16(ka1, aq1, s[j], 0, 0, 0);
        }
        __builtin_amdgcn_s_setprio(0);

        // softmax for q=l15; exp2 domain. Balanced max tree (fmax associative: exact)
        float mj0 = fmaxf(fmaxf(fmaxf(s[0][0], s[0][1]), s[0][2]), s[0][3]);
        float mj1 = fmaxf(fmaxf(fmaxf(s[1][0], s[1][1]), s[1][2]), s[1][3]);
        float mj2 = fmaxf(fmaxf(fmaxf(s[2][0], s[2][1]), s[2][2]), s[2][3]);
        float mj3 = fmaxf(fmaxf(fmaxf(s[3][0], s[3][1]), s[3][2]), s[3][3]);
        float mx = fmaxf(fmaxf(mj0, mj1), fmaxf(mj2, mj3));
        mx = fmaxf(mx, __shfl_xor(mx, 16));
        mx = fmaxf(mx, __shfl_xor(mx, 32));

        // exact-skip rescale: if no row's max grew, al==1.0 exactly for every
        // lane -> skipping the rescale is bitwise identical
        if (!__all(mx <= m_i)) {
            float mnew = fmaxf(m_i, mx);
            float al = __builtin_amdgcn_exp2f(m_i - mnew);
            l_i *= al;
            float alc[4];
            for (int r = 0; r < 4; r++) alc[r] = __shfl(al, quad*4 + r);
            for (int dj = 0; dj < 4; dj++)
                for (int r = 0; r < 4; r++) o[dj][r] *= alc[r];
            m_i = mnew;
        }

        // exp2 + sum with 4 independent partials (ILP on the add chain)
        float rsp[4];
        for (int j = 0; j < 4; j++) {
            float p0 = __builtin_amdgcn_exp2f(s[j][0] - m_i);
            float p1 = __builtin_amdgcn_exp2f(s[j][1] - m_i);
            float p2 = __builtin_amdgcn_exp2f(s[j][2] - m_i);
            float p3 = __builtin_amdgcn_exp2f(s[j][3] - m_i);
            s[j][0] = p0; s[j][1] = p1; s[j][2] = p2; s[j][3] = p3;
            rsp[j] = (p0 + p1) + (p2 + p3);
        }
        float rs = (rsp[0] + rsp[1]) + (rsp[2] + rsp[3]);
        rs += __shfl_xor(rs, 16);
        rs += __shfl_xor(rs, 32);
        l_i += rs;

        // P^T -> Ps (b64 writes; same-wave rows, no barrier needed)
        for (int j = 0; j < 4; j++) {
            bf16x4 pv;
            pv[0] = (bf16)s[j][0]; pv[1] = (bf16)s[j][1];
            pv[2] = (bf16)s[j][2]; pv[3] = (bf16)s[j][3];
            *(bf16x4*)&Ps[w*16 + l15][j*16 + quad*4] = pv;
        }

        // O += P*V  (P fragment via two b64 reads: conflict-free at stride 34)
        __builtin_amdgcn_s_setprio(1);
        for (int kf2 = 0; kf2 < 2; kf2++) {
            bf16x4 apl = *(const bf16x4*)&Ps[w*16 + l15][kf2*32 + quad*8];
            bf16x4 aph = *(const bf16x4*)&Ps[w*16 + l15][kf2*32 + quad*8 + 4];
            bf16x8 ap;
            ap[0]=apl[0]; ap[1]=apl[1]; ap[2]=apl[2]; ap[3]=apl[3];
            ap[4]=aph[0]; ap[5]=aph[1]; ap[6]=aph[2]; ap[7]=aph[3];
            for (int dj = 0; dj < 4; dj++) {
                bf16x8 bv = *(const bf16x8*)&Vts[dj*16 + l15][kf2*32 + quad*8];
                o[dj] = __builtin_amdgcn_mfma_f32_16x16x32_bf16(ap, bv, o[dj], 0, 0, 0);
            }
        }
        __builtin_amdgcn_s_setprio(0);

        // rotate next-tile bias: mask from prefetched regs, cp from LDS (short latency)
        if (more) {
            int knl = (kt+1)*64;
            for (int j = 0; j < 4; j++) {
                float4 cv = *(const float4*)&Cs[knl + j*16 + quad*4];
                bias4[j].x = fmaf(mn4[j].x, LOG2E, -cv.x);
                bias4[j].y = fmaf(mn4[j].y, LOG2E, -cv.y);
                bias4[j].z = fmaf(mn4[j].z, LOG2E, -cv.z);
                bias4[j].w = fmaf(mn4[j].w, LOG2E, -cv.w);
            }
        }
    }

    int b = bh >> 3, h = bh & 7;
    if (ksplit == 1) {
        float lc[4];
        for (int r = 0; r < 4; r++) lc[r] = __shfl(l_i, quad*4 + r);
        for (int dj = 0; dj < 4; dj++) {
            for (int r = 0; r < 4; r++) {
                int n = q0 + w*16 + quad*4 + r;
                out[((size_t)(b*NN + n))*D_MODEL + h*HD + dj*16 + l15] = o[dj][r] / lc[r];
            }
        }
    } else {
        size_t pbase = (size_t)kp * BH * NN;
        for (int dj = 0; dj < 4; dj++) {
            for (int r = 0; r < 4; r++) {
                int n = q0 + w*16 + quad*4 + r;
                op[(pbase + bh*NN + n)*HD + dj*16 + l15] = o[dj][r];
            }
        }
        if (quad == 0) {
            float2 v; v.x = m_i; v.y = l_i;
            *(float2*)(ml + (pbase + (size_t)bh*NN + qrow)*2) = v;
        }
    }
}

// ---------------- kernel 4: combine ksplit partials (exp2 domain) ----------------
__global__ __launch_bounds__(256) void combineN(const float* __restrict__ op,
                                                const float* __restrict__ ml,
                                                float* __restrict__ out,
                                                int ksplit) {
    int idx = blockIdx.x * 256 + threadIdx.x;    // 32768 rows * 16 chunks
    int row = idx >> 4, c4 = (idx & 15) * 4;
    float mstar = -1e30f;
    for (int kp = 0; kp < ksplit; kp++)
        mstar = fmaxf(mstar, ml[((size_t)kp*BH*NN + row)*2]);
    float denom = 0.f;
    float ax = 0.f, ay = 0.f, az = 0.f, aw = 0.f;
    for (int kp = 0; kp < ksplit; kp++) {
        float2 m2 = *(const float2*)(ml + ((size_t)kp*BH*NN + row)*2);
        float wgt = __builtin_amdgcn_exp2f(m2.x - mstar);
        denom += wgt * m2.y;
        float4 ov = *(const float4*)(op + ((size_t)kp*BH*NN + row)*HD + c4);
        ax += wgt*ov.x; ay += wgt*ov.y; az += wgt*ov.z; aw += wgt*ov.w;
    }
    float inv = 1.0f / denom;
    int bh = row >> 11, q = row & 2047;
    int b = bh >> 3, h = bh & 7;
    float4 res; res.x = ax*inv; res.y = ay*inv; res.z = az*inv; res.w = aw*inv;
    *(float4*)(out + ((size_t)(b*NN + q))*D_MODEL + h*HD + c4) = res;
}

extern "C" void kernel_launch(void* const* d_in, const int* in_sizes, int n_in,
                              void* d_out, int out_size, void* d_ws, size_t ws_size,
                              hipStream_t stream) {
    const float* x      = (const float*)d_in[0];
    const float* coords = (const float*)d_in[1];
    const float* amask  = (const float*)d_in[2];
    const float* qkv_w  = (const float*)d_in[3];
    const float* qkv_b  = (const float*)d_in[4];
    const float* rw     = (const float*)d_in[5];
    float* out = (float*)d_out;

    char* ws = (char*)d_ws;
    float* cp  = (float*)(ws + 0);          // 131072
    bf16*  xb  = (bf16*) (ws + 131072);     // 4194304
    bf16*  wb  = (bf16*) (ws + 4325376);    // 1572864
    bf16*  qb  = (bf16*) (ws + 5898240);    // 4194304
    bf16*  kb  = (bf16*) (ws + 10092544);   // 4194304
    bf16*  vtb = (bf16*) (ws + 14286848);   // 4194304
    float* op  = (float*)(ws + 18481152);   // split*8388608

    // split=2: halves the op/ml partials roundtrip vs split=4 while keeping
    // exactly 4 attn blocks/CU co-resident (grid 1024 = 256 CU x 4).
    int split = 1;
    if (ws_size >= 35782656u) split = 2;
    float* ml = (float*)(ws + 18481152 + (size_t)split*8388608);

    convxw   <<<dim3(2832), dim3(256), 0, stream>>>(x, qkv_w, coords, rw, xb, wb, cp);
    qkv_gemm <<<dim3(768),  dim3(256), 0, stream>>>(xb, wb, qkv_b, qb, kb, vtb);
    attn     <<<dim3(512*split), dim3(256), 0, stream>>>(qb, kb, vtb, amask, cp, op, ml, out, split);
    if (split > 1)
        combineN<<<dim3(2048), dim3(256), 0, stream>>>(op, ml, out, split);
}